// Round 8
// baseline (297.301 us; speedup 1.0000x reference)
//
#include <hip/hip_runtime.h>

// LSTM B=8192, T=512, I=1, H=32; out[b] = h_T . W_lin + b_lin.  All I/O f32.
//
// MFMA formulation, 8 waves per 16-batch group (512 blocks x 512 threads).
// wv = tid>>6; half = wv>>2 (hidden half), rsel = wv&3 (D-row select).
// All 4 waves of a half compute the SAME tiles {half,2+half,4+half,6+half}
// (tile 2T+half = gate type T, hiddens [16half,16half+16)) — MFMA duplicated
// 4x (matrix pipe was ~14% busy; it's free) — but each wave activates ONE
// D-row: A-rows loaded permuted by sigma(m)=(m&12)|((m+rsel)&3), which
// permutes D rows identically, so the owned gate (4q+rsel) lands in acc
// slot 0 for every wave -> compile-time slot index.
//   lane(quad,col) owns hidden j = 16half+4quad+rsel of batch col:
//   10 transcendentals per lane-step (the quarter-rate-pipe floor).
// h exchange: ds_write_b16 per lane into double-buffered pair buffer,
// ds_read_b128 B-frag after ONE barrier/step.
// R7 post-mortem: busy = 644 cyc/step at 2 waves/SIMD, trans >60% of busy,
// 36% exposed latency. This split: 4096 waves = 4/SIMD, trans/wave 20->10;
// per-SIMD busy ~584 cyc/step vs 384 device trans floor.
// Pre-acts pre-scaled by log2e (2*log2e for tanh gate):
//   sigmoid(z)=rcp(1+exp2(-acc)), tanh(z)=2*rcp(1+exp2(-2*L2E*z'))-1.

#define L2E 1.4426950408889634f

typedef _Float16 f16x8 __attribute__((ext_vector_type(8)));
typedef float    f32x4 __attribute__((ext_vector_type(4)));

__global__ __launch_bounds__(512, 4) void lstm_mfma8(
    const float* __restrict__ x,      // [B*512]
    const float* __restrict__ W_ih,   // [128]
    const float* __restrict__ W_hh,   // [128*32]
    const float* __restrict__ b_ih,   // [128]
    const float* __restrict__ b_hh,   // [128]
    const float* __restrict__ W_lin,  // [32]
    const float* __restrict__ b_lin,  // [1]
    float* __restrict__ out)          // [B]
{
    __shared__ float xs[512 * 17];                        // x transposed [t][b], stride 17
    __shared__ __align__(16) unsigned int hb[2][16 * 20]; // h pair buffers, col-stride 20 uints
    __shared__ float ps[128];                             // epilogue partials

    const int tid  = threadIdx.x;
    const int wv   = tid >> 6;         // 0..7
    const int half = wv >> 2;          // hidden half 0/1
    const int rsel = wv & 3;           // D-row select 0..3
    const int lane = tid & 63;
    const int col  = lane & 15;        // batch within group
    const int quad = lane >> 4;        // 0..3
    const int base = blockIdx.x * 16;  // global batch base

    // ---- stage x[base..base+15][0..511] into LDS transposed ----
    {
        const float4* xg = (const float4*)(x + (size_t)base * 512);
        #pragma unroll
        for (int it = 0; it < 4; ++it) {
            int idx = it * 512 + tid;          // 0..2047 float4s
            float4 v = xg[idx];
            int b  = idx >> 7;                 // batch 0..15
            int t0 = (idx & 127) * 4;
            xs[(t0 + 0) * 17 + b] = v.x;
            xs[(t0 + 1) * 17 + b] = v.y;
            xs[(t0 + 2) * 17 + b] = v.z;
            xs[(t0 + 3) * 17 + b] = v.w;
        }
    }

    // ---- per-wave weights: tiles 2T+half, A-rows rotated within row-quads ----
    f16x8 wA[4];
    float wih1[4], bia1[4];
    const int srow = (col & 12) | ((col + rsel) & 3);     // sigma(col)
    #pragma unroll
    for (int T = 0; T < 4; ++T) {
        const int tile = 2 * T + half;
        const float s = (T == 2) ? (2.0f * L2E) : L2E;
        const int ga = 16 * tile + srow;                  // permuted A row
        #pragma unroll
        for (int j = 0; j < 8; ++j)
            wA[T][j] = (_Float16)(W_hh[ga * 32 + quad * 8 + j] * s);
        const int g = 16 * tile + quad * 4 + rsel;        // owned gate row
        wih1[T] = W_ih[g] * s;
        bia1[T] = (b_ih[g] + b_hh[g]) * s;
    }
    const int jj = 16 * half + 4 * quad + rsel;           // owned hidden 0..31
    const float wl = W_lin[jj];

    __syncthreads();

    float c0 = 0.0f, h0 = 0.0f;
    f16x8 bfrag = {};                  // h = 0
    // C-operand: slot 0 live (owned gate), slots 1..3 stay zero forever
    f32x4 cq[4] = {{0,0,0,0}, {0,0,0,0}, {0,0,0,0}, {0,0,0,0}};
    {
        float xt = xs[col];            // t = 0
        #pragma unroll
        for (int T = 0; T < 4; ++T)
            cq[T][0] = fmaf(xt, wih1[T], bia1[T]);
    }

    #pragma unroll 2
    for (int t = 0; t < 512; ++t) {
        unsigned int* buf = hb[t & 1];

        f32x4 acc[4];
        #pragma unroll
        for (int T = 0; T < 4; ++T)
            acc[T] = __builtin_amdgcn_mfma_f32_16x16x32_f16(wA[T], bfrag, cq[T], 0, 0, 0);

        float xt1 = xs[((t + 1) & 511) * 17 + col];       // prefetch next x

        // activations for the single owned hidden (slot 0)
        float ei = __builtin_amdgcn_exp2f(-acc[0][0]);
        float ef = __builtin_amdgcn_exp2f(-acc[1][0]);
        float eg = __builtin_amdgcn_exp2f(-acc[2][0]);
        float eo = __builtin_amdgcn_exp2f(-acc[3][0]);
        float si = __builtin_amdgcn_rcpf(1.0f + ei);
        float sf = __builtin_amdgcn_rcpf(1.0f + ef);
        float sg = __builtin_amdgcn_rcpf(1.0f + eg);
        float so = __builtin_amdgcn_rcpf(1.0f + eo);
        float gg = fmaf(2.0f, sg, -1.0f);                 // tanh(gate)
        c0 = fmaf(sf, c0, si * gg);
        float tc = __builtin_amdgcn_rcpf(1.0f + __builtin_amdgcn_exp2f(c0 * (-2.0f * L2E)));
        h0 = so * fmaf(2.0f, tc, -1.0f);                  // o * tanh(c)

        // write this lane's h as one f16 halfword: short index col*40 + jj
        ((short*)buf)[col * 40 + jj] =
            (short)__builtin_bit_cast(unsigned short, (_Float16)h0);

        // next step's C-init in the pre-barrier slack
        #pragma unroll
        for (int T = 0; T < 4; ++T)
            cq[T][0] = fmaf(xt1, wih1[T], bia1[T]);

        __syncthreads();
        // B-frag: pairs quad*4..+3 of batch col = k quad*8..quad*8+7
        uint4 bv = *(const uint4*)&buf[col * 20 + quad * 4];
        bfrag = __builtin_bit_cast(f16x8, bv);
    }

    // ---- epilogue: out[b] = sum_j h_j * W_lin[j] + b_lin ----
    float v = h0 * wl;
    v += __shfl_xor(v, 16);            // combine quads
    v += __shfl_xor(v, 32);
    if (lane < 16) ps[wv * 16 + col] = v;
    __syncthreads();
    if (tid < 16) {
        float s = b_lin[0];
        #pragma unroll
        for (int w = 0; w < 8; ++w) s += ps[w * 16 + tid];
        out[base + tid] = s;
    }
}

extern "C" void kernel_launch(void* const* d_in, const int* in_sizes, int n_in,
                              void* d_out, int out_size, void* d_ws, size_t ws_size,
                              hipStream_t stream) {
    const float* x     = (const float*)d_in[0];
    const float* W_ih  = (const float*)d_in[1];
    const float* W_hh  = (const float*)d_in[2];
    const float* b_ih  = (const float*)d_in[3];
    const float* b_hh  = (const float*)d_in[4];
    const float* W_lin = (const float*)d_in[5];
    const float* b_lin = (const float*)d_in[6];
    float* out = (float*)d_out;

    const int B = in_sizes[0] / 512;   // 8192
    dim3 grid(B / 16), block(512);
    lstm_mfma8<<<grid, block, 0, stream>>>(x, W_ih, W_hh, b_ih, b_hh, W_lin, b_lin, out);
}